// Round 1
// baseline (1271.593 us; speedup 1.0000x reference)
//
#include <hip/hip_runtime.h>

#define N_NODES 50000
#define DIM 128
#define N_LAYERS 5
#define BN_EPS 1e-5f

// ---------------- CSR build ----------------

__global__ void hist_kernel(const int* __restrict__ dst, int n_edges, int* __restrict__ counts) {
    int e = blockIdx.x * 256 + threadIdx.x;
    if (e < n_edges) atomicAdd(&counts[dst[e]], 1);
}

__global__ void scan_local(const int* __restrict__ counts, int n,
                           int* __restrict__ offsets, int* __restrict__ blocksums) {
    __shared__ int temp[256];
    int t = threadIdx.x;
    int i = blockIdx.x * 256 + t;
    int v = (i < n) ? counts[i] : 0;
    temp[t] = v;
    __syncthreads();
    for (int off = 1; off < 256; off <<= 1) {
        int add = (t >= off) ? temp[t - off] : 0;
        __syncthreads();
        temp[t] += add;
        __syncthreads();
    }
    if (i < n) offsets[i] = temp[t] - v;   // exclusive within block
    if (t == 255) blocksums[blockIdx.x] = temp[255];
}

__global__ void scan_block(int* __restrict__ blocksums, int nb) {
    __shared__ int temp[256];
    int t = threadIdx.x;
    int v = (t < nb) ? blocksums[t] : 0;
    temp[t] = v;
    __syncthreads();
    for (int off = 1; off < 256; off <<= 1) {
        int add = (t >= off) ? temp[t - off] : 0;
        __syncthreads();
        temp[t] += add;
        __syncthreads();
    }
    if (t < nb) blocksums[t] = temp[t] - v;  // exclusive
}

__global__ void scan_add(int* __restrict__ offsets, int* __restrict__ cursor,
                         const int* __restrict__ blocksums, int n, int n_edges) {
    int i = blockIdx.x * 256 + threadIdx.x;
    if (i < n) {
        int val = offsets[i] + blocksums[blockIdx.x];
        offsets[i] = val;
        cursor[i] = val;
    }
    if (i == 0) offsets[n] = n_edges;
}

__global__ void scatter_kernel(const int* __restrict__ src, const int* __restrict__ dst,
                               int n_edges, int* __restrict__ cursor, int* __restrict__ csr_src) {
    int e = blockIdx.x * 256 + threadIdx.x;
    if (e < n_edges) {
        int p = atomicAdd(&cursor[dst[e]], 1);
        csr_src[p] = src[e];
    }
}

// ---------------- per-layer kernels ----------------

// one wave (64 lanes) per node; lane handles 2 dims (float2)
__global__ void agg_kernel(const float* __restrict__ x, const int* __restrict__ csr_src,
                           const int* __restrict__ offsets, float* __restrict__ h_pre) {
    int wave = threadIdx.x >> 6;
    int lane = threadIdx.x & 63;
    int node = blockIdx.x * 4 + wave;
    if (node >= N_NODES) return;
    int beg = offsets[node], end = offsets[node + 1];
    float2 acc = *(const float2*)(x + (size_t)node * DIM + lane * 2);  // h = x + agg
    for (int e = beg; e < end; ++e) {
        int s = csr_src[e];
        float2 v = *(const float2*)(x + (size_t)s * DIM + lane * 2);
        acc.x += v.x;
        acc.y += v.y;
    }
    *(float2*)(h_pre + (size_t)node * DIM + lane * 2) = acc;
}

#define TILE 16

// fused: h_tile -> ReLU(h@W1+b1) -> @W2+b2 -> ReLU -> h_post + BN partial sums
__global__ __launch_bounds__(256) void mlp_kernel(
        const float* __restrict__ h_pre,
        const float* __restrict__ W1, const float* __restrict__ b1,
        const float* __restrict__ W2, const float* __restrict__ b2,
        float* __restrict__ h_post,
        float* __restrict__ bn_sum, float* __restrict__ bn_sumsq) {
    __shared__ float h_lds[TILE * DIM];
    __shared__ float mid_lds[TILE * DIM];
    __shared__ float red_s[2 * DIM];
    __shared__ float red_q[2 * DIM];
    int t = threadIdx.x;
    int row0 = blockIdx.x * TILE;

    for (int idx = t; idx < TILE * DIM; idx += 256) {
        int r = idx >> 7;
        int grow = row0 + r;
        h_lds[idx] = (grow < N_NODES) ? h_pre[(size_t)grow * DIM + (idx & 127)] : 0.0f;
    }
    __syncthreads();

    int col = t & 127;
    int rg = t >> 7;         // 0 or 1 (wave-uniform)
    int rbase = rg * 8;

    float acc[8];
    float bv = b1[col];
#pragma unroll
    for (int r = 0; r < 8; ++r) acc[r] = bv;
    for (int k = 0; k < DIM; ++k) {
        float w = W1[k * DIM + col];
#pragma unroll
        for (int r = 0; r < 8; ++r) acc[r] += h_lds[(rbase + r) * DIM + k] * w;
    }
#pragma unroll
    for (int r = 0; r < 8; ++r) mid_lds[(rbase + r) * DIM + col] = fmaxf(acc[r], 0.0f);
    __syncthreads();

    bv = b2[col];
#pragma unroll
    for (int r = 0; r < 8; ++r) acc[r] = bv;
    for (int k = 0; k < DIM; ++k) {
        float w = W2[k * DIM + col];
#pragma unroll
        for (int r = 0; r < 8; ++r) acc[r] += mid_lds[(rbase + r) * DIM + k] * w;
    }

    float psum = 0.0f, psq = 0.0f;
#pragma unroll
    for (int r = 0; r < 8; ++r) {
        float o = fmaxf(acc[r], 0.0f);   // outer ReLU
        int grow = row0 + rbase + r;
        if (grow < N_NODES) {
            h_post[(size_t)grow * DIM + col] = o;
            psum += o;
            psq += o * o;
        }
    }
    red_s[rg * DIM + col] = psum;
    red_q[rg * DIM + col] = psq;
    __syncthreads();
    if (rg == 0) {
        atomicAdd(&bn_sum[col], red_s[col] + red_s[DIM + col]);
        atomicAdd(&bn_sumsq[col], red_q[col] + red_q[DIM + col]);
    }
}

__global__ void bn_apply(float* __restrict__ h,
                         const float* __restrict__ bn_sum, const float* __restrict__ bn_sumsq,
                         const float* __restrict__ gamma, const float* __restrict__ beta) {
    int idx = blockIdx.x * 256 + threadIdx.x;
    if (idx >= N_NODES * DIM) return;
    int col = idx & 127;
    const float invN = 1.0f / (float)N_NODES;
    float mean = bn_sum[col] * invN;
    float var = bn_sumsq[col] * invN - mean * mean;
    var = fmaxf(var, 0.0f);
    float inv = rsqrtf(var + BN_EPS);
    h[idx] = (h[idx] - mean) * inv * gamma[col] + beta[col];
}

// ---------------- launch ----------------

extern "C" void kernel_launch(void* const* d_in, const int* in_sizes, int n_in,
                              void* d_out, int out_size, void* d_ws, size_t ws_size,
                              hipStream_t stream) {
    const float* x     = (const float*)d_in[0];
    const int*   eidx  = (const int*)d_in[1];
    const float* W1    = (const float*)d_in[3];
    const float* b1    = (const float*)d_in[4];
    const float* W2    = (const float*)d_in[5];
    const float* b2    = (const float*)d_in[6];
    const float* gamma = (const float*)d_in[7];
    const float* beta  = (const float*)d_in[8];

    int n_edges = in_sizes[1] / 2;
    const int* src = eidx;
    const int* dst = eidx + n_edges;

    int* counts    = (int*)d_ws;               // 50000
    int* offsets   = counts + N_NODES;         // 50001
    int* cursor    = offsets + N_NODES + 1;    // 50000
    int* blocksums = cursor + N_NODES;         // 256
    int* csr_src   = blocksums + 256;          // n_edges
    float* bn_sum   = (float*)(csr_src + n_edges);  // 128
    float* bn_sumsq = bn_sum + DIM;                 // 128

    float* out = (float*)d_out;
    float* h_scratch = out;   // [0, N*D) reused as h_pre scratch; overwritten at end

    hipMemsetAsync(counts, 0, N_NODES * sizeof(int), stream);
    hist_kernel<<<(n_edges + 255) / 256, 256, 0, stream>>>(dst, n_edges, counts);
    int nb = (N_NODES + 255) / 256;  // 196
    scan_local<<<nb, 256, 0, stream>>>(counts, N_NODES, offsets, blocksums);
    scan_block<<<1, 256, 0, stream>>>(blocksums, nb);
    scan_add<<<nb, 256, 0, stream>>>(offsets, cursor, blocksums, N_NODES, n_edges);
    scatter_kernel<<<(n_edges + 255) / 256, 256, 0, stream>>>(src, dst, n_edges, cursor, csr_src);

    const float* layer_in = x;
    for (int i = 0; i < N_LAYERS; ++i) {
        float* layer_out = out + (size_t)(1 + i) * N_NODES * DIM;
        hipMemsetAsync(bn_sum, 0, 2 * DIM * sizeof(float), stream);
        agg_kernel<<<(N_NODES + 3) / 4, 256, 0, stream>>>(layer_in, csr_src, offsets, h_scratch);
        mlp_kernel<<<(N_NODES + TILE - 1) / TILE, 256, 0, stream>>>(
            h_scratch, W1 + (size_t)i * DIM * DIM, b1 + (size_t)i * DIM,
            W2 + (size_t)i * DIM * DIM, b2 + (size_t)i * DIM,
            layer_out, bn_sum, bn_sumsq);
        bn_apply<<<(N_NODES * DIM + 255) / 256, 256, 0, stream>>>(
            layer_out, bn_sum, bn_sumsq, gamma + (size_t)i * DIM, beta + (size_t)i * DIM);
        layer_in = layer_out;
    }
    hipMemcpyAsync(out, out + (size_t)N_LAYERS * N_NODES * DIM,
                   (size_t)N_NODES * DIM * sizeof(float), hipMemcpyDeviceToDevice, stream);
}